// Round 4
// baseline (235.079 us; speedup 1.0000x reference)
//
#include <hip/hip_runtime.h>
#include <math.h>

#define B_    256
#define I_    1152
#define J_    10
#define DIN_  8
#define DOUT_ 16

// s_accum tiling: 64 batches x 16 i's x 5 j's per block; 256 thr = 16 slot x 16 d,
// each thread handles 4 batches (slot, slot+16, slot+32, slot+48).
#define BB   64
#define NBC  (B_/BB)     // 4 batch chunks
#define IC   16
#define NIC  (I_/IC)     // 72 i chunks
#define JG   5
#define NJG  (J_/JG)     // 2 j groups
#define QB   4           // batches per thread
// grid = NBC*NIC*NJG = 576 blocks; LDS 73 KB -> 2 blocks/CU

// ---------------------------------------------------------------------------
// Phase A: s_acc[b,j,d] += sum_i softmax(b)[i,j] * (W[i,j,d,:].x[b,i,:])
// W tile staged in LDS (d-innermost, pre-scaled by coupling coeff c);
// 4 batches per thread amortize every W read / address calc over 4x FMAs.
// ---------------------------------------------------------------------------
__global__ __launch_bounds__(256)
void s_accum_kernel(const float* __restrict__ x, const float* __restrict__ W,
                    const float* __restrict__ blog, float* __restrict__ s_acc)
{
    const int tid = threadIdx.x;
    const int bc  = blockIdx.x & (NBC - 1);
    const int t   = blockIdx.x >> 2;
    const int jg  = t / NIC;
    const int ic  = t - jg * NIC;
    const int j0  = jg * JG;
    const int i0  = ic * IC;
    const int b0  = bc * BB;
    const int slot = tid >> 4;                // 0..15
    const int d    = tid & 15;                // 0..15

    __shared__ float4 w_lds[IC * JG * 32];    // 2560 f4 = 40 KB
    __shared__ float4 x_lds[BB * IC * 2];     // 2048 f4 = 32 KB
    __shared__ float  c_lds[IC * JG];         // 80 f

    // --- stage W tile (raw); within an (il,jj) row, f4 index r2 = d*2+k4
    const float4* Wg = (const float4*)W;
    #pragma unroll
    for (int idx = tid; idx < IC * JG * 32; idx += 256) {
        int row = idx >> 5;                   // il*JG + jj
        int r2  = idx & 31;
        int il  = row / JG;
        int jj  = row - il * JG;
        int dd  = r2 >> 1;
        int k4  = r2 & 1;
        float4 v = Wg[(size_t)(i0 + il) * (J_ * 32) + (size_t)(j0 + jj) * 32 + r2];
        w_lds[(row * 2 + k4) * 16 + dd] = v;  // d-innermost
    }
    // --- stage x tile: x[b0..b0+63, i0..i0+15, :] (32 f4 per batch row)
    #pragma unroll
    for (int idx = tid; idx < BB * 32; idx += 256) {
        int bl = idx >> 5;
        int r  = idx & 31;
        x_lds[idx] = ((const float4*)(x + (size_t)(b0 + bl) * I_ * DIN_
                                        + (size_t)i0 * DIN_))[r];
    }
    // --- softmax over all 10 j; keep our 5
    if (tid < IC) {
        const float* br = blog + (size_t)(i0 + tid) * J_;
        float bv[J_];
        float mx = -1e30f;
        #pragma unroll
        for (int j = 0; j < J_; ++j) { bv[j] = br[j]; mx = fmaxf(mx, bv[j]); }
        float sum = 0.f;
        #pragma unroll
        for (int j = 0; j < J_; ++j) { bv[j] = __expf(bv[j] - mx); sum += bv[j]; }
        float inv = 1.f / sum;
        #pragma unroll
        for (int jj = 0; jj < JG; ++jj) c_lds[tid * JG + jj] = bv[j0 + jj] * inv;
    }
    __syncthreads();

    // --- scale staged W by c
    #pragma unroll
    for (int idx = tid; idx < IC * JG * 32; idx += 256) {
        float c = c_lds[idx >> 5];
        float4 v = w_lds[idx];
        v.x *= c; v.y *= c; v.z *= c; v.w *= c;
        w_lds[idx] = v;
    }
    __syncthreads();

    float acc[QB][JG];
    #pragma unroll
    for (int q = 0; q < QB; ++q)
        #pragma unroll
        for (int jj = 0; jj < JG; ++jj) acc[q][jj] = 0.f;

    #pragma unroll 4
    for (int il = 0; il < IC; ++il) {
        float4 xa[QB], xb[QB];
        #pragma unroll
        for (int q = 0; q < QB; ++q) {
            int bl = slot + 16 * q;
            xa[q] = x_lds[(bl * IC + il) * 2 + 0];
            xb[q] = x_lds[(bl * IC + il) * 2 + 1];
        }
        const float4* wrow = &w_lds[il * JG * 32];
        #pragma unroll
        for (int jj = 0; jj < JG; ++jj) {
            float4 w0 = wrow[jj * 32 + d];
            float4 w1 = wrow[jj * 32 + 16 + d];
            #pragma unroll
            for (int q = 0; q < QB; ++q) {
                acc[q][jj] += w0.x * xa[q].x + w0.y * xa[q].y
                            + w0.z * xa[q].z + w0.w * xa[q].w
                            + w1.x * xb[q].x + w1.y * xb[q].y
                            + w1.z * xb[q].z + w1.w * xb[q].w;
            }
        }
    }

    #pragma unroll
    for (int q = 0; q < QB; ++q) {
        float* sp = s_acc + (size_t)(b0 + slot + 16 * q) * J_ * DOUT_
                          + (size_t)j0 * DOUT_ + d;
        #pragma unroll
        for (int jj = 0; jj < JG; ++jj)
            atomicAdd(sp + jj * DOUT_, acc[q][jj]);
    }
}

// ---------------------------------------------------------------------------
// squash: s = v*|v|/(1+|v|^2); writes s_out [b,j,d] and transposed s_t [j,b,d];
// re-zeros s_acc.
// ---------------------------------------------------------------------------
__global__ __launch_bounds__(256)
void squash_kernel(float* __restrict__ s_acc, float* __restrict__ s_out,
                   float* __restrict__ s_t)
{
    int gid = blockIdx.x * 256 + threadIdx.x;   // 40960
    float v  = s_acc[gid];
    float sq = v * v;
    #pragma unroll
    for (int off = 1; off < 16; off <<= 1)
        sq += __shfl_xor(sq, off, 16);
    float l2 = sqrtf(sq);
    float val = v * (l2 / (1.f + sq));
    s_out[gid] = val;
    int b  = gid / (J_ * DOUT_);
    int jd = gid - b * (J_ * DOUT_);
    int j  = jd >> 4;
    int dd = jd & 15;
    s_t[((size_t)j * B_ + b) * DOUT_ + dd] = val;
    s_acc[gid] = 0.f;
}

// ---------------------------------------------------------------------------
// Phase B: blog[i,j] += sum_{b,d} (W[i,j,d,:].x[b,i,:]) * s[b,j,d]
// One block per i; thread = batch. W[i] row (5 KB) staged in LDS (broadcast
// reads); s read coalesced from transposed s_t.
// ---------------------------------------------------------------------------
__global__ __launch_bounds__(256)
void b_update_kernel(const float* __restrict__ x, const float* __restrict__ W,
                     const float* __restrict__ s_t, float* __restrict__ blog)
{
    const int i    = blockIdx.x;
    const int tb   = threadIdx.x;   // batch index
    const int lane = tb & 63;
    const int wid  = tb >> 6;

    __shared__ float4 w_lds[J_ * DOUT_ * 2];   // 320 f4 = 5 KB
    __shared__ float wred[J_][4];

    const float4* Wg = (const float4*)W + (size_t)i * (J_ * DOUT_ * 2);
    #pragma unroll
    for (int idx = tb; idx < J_ * DOUT_ * 2; idx += 256)
        w_lds[idx] = Wg[idx];

    const float4* xp = (const float4*)(x + ((size_t)tb * I_ + i) * DIN_);
    float4 xa = xp[0];
    float4 xb = xp[1];
    __syncthreads();

    #pragma unroll
    for (int j = 0; j < J_; ++j) {
        const float4* sp = (const float4*)(s_t + ((size_t)j * B_ + tb) * DOUT_);
        float4 s0 = sp[0], s1 = sp[1], s2 = sp[2], s3 = sp[3];
        const float sv[DOUT_] = {s0.x, s0.y, s0.z, s0.w,
                                 s1.x, s1.y, s1.z, s1.w,
                                 s2.x, s2.y, s2.z, s2.w,
                                 s3.x, s3.y, s3.z, s3.w};
        float accj = 0.f;
        #pragma unroll
        for (int d = 0; d < DOUT_; ++d) {
            float4 w0 = w_lds[(j * DOUT_ + d) * 2 + 0];   // broadcast
            float4 w1 = w_lds[(j * DOUT_ + d) * 2 + 1];
            float dot = w0.x * xa.x + w0.y * xa.y + w0.z * xa.z + w0.w * xa.w
                      + w1.x * xb.x + w1.y * xb.y + w1.z * xb.z + w1.w * xb.w;
            accj = fmaf(dot, sv[d], accj);
        }
        #pragma unroll
        for (int off = 32; off >= 1; off >>= 1)
            accj += __shfl_xor(accj, off, 64);
        if (lane == 0) wred[j][wid] = accj;
    }
    __syncthreads();
    if (tb < J_) {
        float v = wred[tb][0] + wred[tb][1] + wred[tb][2] + wred[tb][3];
        blog[(size_t)i * J_ + tb] += v;
    }
}

// ---------------------------------------------------------------------------
extern "C" void kernel_launch(void* const* d_in, const int* in_sizes, int n_in,
                              void* d_out, int out_size, void* d_ws, size_t ws_size,
                              hipStream_t stream)
{
    const float* x = (const float*)d_in[0];   // [B, I, DIN]
    const float* W = (const float*)d_in[1];   // [I, J, DOUT, DIN]
    float* s_out = (float*)d_out;             // [B, J, DOUT]
    float* s_acc = (float*)d_ws;                         // 40960 f
    float* blog  = s_acc + B_ * J_ * DOUT_;              // 11520 f
    float* s_t   = blog + I_ * J_;                       // 40960 f (transposed s)

    hipMemsetAsync(d_ws, 0, (size_t)(B_ * J_ * DOUT_ + I_ * J_) * sizeof(float),
                   stream);

    for (int it = 0; it < 3; ++it) {
        s_accum_kernel<<<NBC * NIC * NJG, 256, 0, stream>>>(x, W, blog, s_acc);
        squash_kernel<<<(B_ * J_ * DOUT_) / 256, 256, 0, stream>>>(s_acc, s_out, s_t);
        if (it < 2)
            b_update_kernel<<<I_, 256, 0, stream>>>(x, W, s_t, blog);
    }
}

// Round 7
// 206.626 us; speedup vs baseline: 1.1377x; 1.1377x over previous
//
#include <hip/hip_runtime.h>
#include <math.h>

typedef unsigned short ushort_t;
typedef __attribute__((ext_vector_type(8))) __bf16 bf16x8;
typedef __attribute__((ext_vector_type(4))) float floatx4;

#define B_    256
#define I_    1152
#define J_    10
#define DIN_  8
#define DOUT_ 16
#define K_    (I_*DIN_)     // 9216
#define N_    (J_*DOUT_)    // 160
#define NSPLIT 8
#define KCHUNK (K_/NSPLIT)  // 1152
#define KSTEPS (KCHUNK/32)  // 36

static __device__ __forceinline__ ushort_t f2bf(float f) {
    unsigned int u = __float_as_uint(f);
    u += 0x7fffu + ((u >> 16) & 1u);     // RNE
    return (ushort_t)(u >> 16);
}
static __device__ __forceinline__ float bf2f(ushort_t h) {
    return __uint_as_float(((unsigned int)h) << 16);
}

// --- one-time prep: Xt hi/lo bf16 [K][B] (transpose + Dekker split) ---
__global__ __launch_bounds__(256)
void prep_xt_kernel(const float* __restrict__ x, ushort_t* __restrict__ Xt_hi,
                    ushort_t* __restrict__ Xt_lo)
{
    int t = blockIdx.x * 256 + threadIdx.x;       // 589824
    int k  = t >> 6;
    int b0 = (t & 63) * 4;
    ushort4 hi, lo;
    float v;
    v = x[(size_t)(b0 + 0) * K_ + k]; hi.x = f2bf(v); lo.x = f2bf(v - bf2f(hi.x));
    v = x[(size_t)(b0 + 1) * K_ + k]; hi.y = f2bf(v); lo.y = f2bf(v - bf2f(hi.y));
    v = x[(size_t)(b0 + 2) * K_ + k]; hi.z = f2bf(v); lo.z = f2bf(v - bf2f(hi.z));
    v = x[(size_t)(b0 + 3) * K_ + k]; hi.w = f2bf(v); lo.w = f2bf(v - bf2f(hi.w));
    ((ushort4*)Xt_hi)[(size_t)k * 64 + (t & 63)] = hi;
    ((ushort4*)Xt_lo)[(size_t)k * 64 + (t & 63)] = lo;
}

// --- per-iteration: coupling coefficients c[i][j] = softmax(blog[i,:]) ---
__global__ __launch_bounds__(256)
void c_kernel(const float* __restrict__ blog, float* __restrict__ c)
{
    int i = blockIdx.x * 256 + threadIdx.x;
    if (i >= I_) return;
    float bv[J_];
    float mx = -1e30f;
    #pragma unroll
    for (int j = 0; j < J_; ++j) { bv[j] = blog[i * J_ + j]; mx = fmaxf(mx, bv[j]); }
    float sum = 0.f;
    #pragma unroll
    for (int j = 0; j < J_; ++j) { bv[j] = __expf(bv[j] - mx); sum += bv[j]; }
    float inv = 1.f / sum;
    #pragma unroll
    for (int j = 0; j < J_; ++j) c[i * J_ + j] = bv[j] * inv;
}

// --- s-GEMM: S = X @ (c ∘ W)^T, M=256 N=160 K=9216, split-K=8.
// Both operands loaded fp32 and Dekker-split in-register; 3 MFMAs/step
// (hi.hi + lo.hi + hi.lo) => fp32-equivalent product precision.
__global__ __launch_bounds__(256)
void gemm_s_kernel(const float* __restrict__ x, const float* __restrict__ W,
                   const float* __restrict__ c, floatx4* __restrict__ P)
{
    int wv   = blockIdx.x * 4 + (threadIdx.x >> 6);   // 0..1279
    int lane = threadIdx.x & 63;
    int tile = wv % 160;
    int ks   = wv / 160;
    int mb = tile / J_, nt = tile % J_;
    int r = lane & 15, q = lane >> 4;
    // A row b = mb*16+r, k-frag base = ks*KCHUNK + 8q (x is [b][k], k=i*8+d)
    const float* ap = x + (size_t)(mb * 16 + r) * K_ + ks * KCHUNK + 8 * q;
    // B row (j=nt, o=r); k-frag covers i = ks*144 + 4s + q, d=0..7
    const float* wp = W + (((size_t)(ks * 144 + q) * J_ + nt) * DOUT_ + r) * DIN_;
    const float* cp = c + (ks * 144 + q) * J_ + nt;
    floatx4 acc = {0.f, 0.f, 0.f, 0.f};
    #pragma unroll 4
    for (int s = 0; s < KSTEPS; ++s) {
        float4 xa0 = *(const float4*)(ap + s * 32);
        float4 xa1 = *(const float4*)(ap + s * 32 + 4);
        float4 w0  = *(const float4*)(wp + (size_t)s * 4 * J_ * DOUT_ * DIN_);
        float4 w1  = *(const float4*)(wp + (size_t)s * 4 * J_ * DOUT_ * DIN_ + 4);
        float cs   = cp[s * 4 * J_];
        float xv[8] = {xa0.x, xa0.y, xa0.z, xa0.w, xa1.x, xa1.y, xa1.z, xa1.w};
        float wvv[8] = {w0.x, w0.y, w0.z, w0.w, w1.x, w1.y, w1.z, w1.w};
        bf16x8 ah, al, bh, bl;
        #pragma unroll
        for (int e = 0; e < 8; ++e) {
            float xe = xv[e];
            __bf16 h = (__bf16)xe;
            ah[e] = h;
            al[e] = (__bf16)(xe - (float)h);
            float pe = wvv[e] * cs;
            __bf16 g = (__bf16)pe;
            bh[e] = g;
            bl[e] = (__bf16)(pe - (float)g);
        }
        acc = __builtin_amdgcn_mfma_f32_16x16x32_bf16(ah, bh, acc, 0, 0, 0);
        acc = __builtin_amdgcn_mfma_f32_16x16x32_bf16(al, bh, acc, 0, 0, 0);
        acc = __builtin_amdgcn_mfma_f32_16x16x32_bf16(ah, bl, acc, 0, 0, 0);
    }
    P[(size_t)(ks * 160 + tile) * 64 + lane] = acc;
}

// --- reduce split-K partials + squash; emit s_out fp32 and Sbt hi/lo bf16 [(j,o)][b]
__global__ __launch_bounds__(256)
void reduce_squash_kernel(const float* __restrict__ P, float* __restrict__ s_out,
                          ushort_t* __restrict__ Sbt_hi, ushort_t* __restrict__ Sbt_lo)
{
    int t = blockIdx.x * 256 + threadIdx.x;   // 40960
    int b  = t / N_;
    int rr = t - b * N_;                      // jo
    int j = rr >> 4, o = rr & 15;
    int tile = (b >> 4) * J_ + j;
    int lane = (((b & 15) >> 2) << 4) | o;    // C/D: col=lane&15, row=(lane>>4)*4+reg
    int reg  = b & 3;
    float v = 0.f;
    #pragma unroll
    for (int ks = 0; ks < NSPLIT; ++ks)
        v += P[((size_t)(ks * 160 + tile) * 64 + lane) * 4 + reg];
    float sq = v * v;
    #pragma unroll
    for (int off = 1; off < 16; off <<= 1)
        sq += __shfl_xor(sq, off, 16);
    float l2 = sqrtf(sq);
    float val = v * (l2 / (1.f + sq));
    s_out[t] = val;
    ushort_t hi = f2bf(val);
    Sbt_hi[(size_t)rr * B_ + b] = hi;
    Sbt_lo[(size_t)rr * B_ + b] = f2bf(val - bf2f(hi));
}

// --- b-update GEMM: T2 = Xt @ S' (M=9216 N=160 K=256), hi/lo split both sides,
// contracted with fp32 W in-register. Unique (i,j) writer per half-wave.
__global__ __launch_bounds__(256)
void gemm_bupd_kernel(const ushort_t* __restrict__ Xt_hi, const ushort_t* __restrict__ Xt_lo,
                      const ushort_t* __restrict__ Sbt_hi, const ushort_t* __restrict__ Sbt_lo,
                      const float* __restrict__ W, float* __restrict__ blog)
{
    int wv   = blockIdx.x * 4 + (threadIdx.x >> 6);   // 0..5759
    int lane = threadIdx.x & 63;
    int mt = wv / J_;                                 // 0..575
    int j  = wv - mt * J_;
    int r = lane & 15, q = lane >> 4;
    size_t aoff = (size_t)(mt * 16 + r) * B_ + 8 * q;
    size_t boff = (size_t)(j * 16 + r) * B_ + 8 * q;
    floatx4 acc = {0.f, 0.f, 0.f, 0.f};
    #pragma unroll
    for (int s = 0; s < B_ / 32; ++s) {
        bf16x8 ah = *(const bf16x8*)(Xt_hi + aoff + s * 32);
        bf16x8 al = *(const bf16x8*)(Xt_lo + aoff + s * 32);
        bf16x8 bh = *(const bf16x8*)(Sbt_hi + boff + s * 32);
        bf16x8 bl = *(const bf16x8*)(Sbt_lo + boff + s * 32);
        acc = __builtin_amdgcn_mfma_f32_16x16x32_bf16(ah, bh, acc, 0, 0, 0);
        acc = __builtin_amdgcn_mfma_f32_16x16x32_bf16(al, bh, acc, 0, 0, 0);
        acc = __builtin_amdgcn_mfma_f32_16x16x32_bf16(ah, bl, acc, 0, 0, 0);
    }
    // rows q*4+reg -> i = mt*2 + (q>>1), d = (q&1)*4 + reg; col -> o = lane&15
    int i  = mt * 2 + (q >> 1);
    int d0 = (q & 1) * 4;
    int o  = lane & 15;
    const float4 w4 = *(const float4*)(W + ((((size_t)i * J_ + j) * DOUT_ + o) * DIN_ + d0));
    float val = acc[0] * w4.x + acc[1] * w4.y + acc[2] * w4.z + acc[3] * w4.w;
    #pragma unroll
    for (int off = 1; off < 32; off <<= 1)
        val += __shfl_xor(val, off, 32);
    if ((lane & 31) == 0)
        blog[(size_t)(mt * 2 + (lane >> 5)) * J_ + j] += val;   // unique writer
}

// ---------------------------------------------------------------------------
extern "C" void kernel_launch(void* const* d_in, const int* in_sizes, int n_in,
                              void* d_out, int out_size, void* d_ws, size_t ws_size,
                              hipStream_t stream)
{
    const float* x = (const float*)d_in[0];   // [B, I, DIN]
    const float* W = (const float*)d_in[1];   // [I, J, DOUT, DIN]
    float* s_out = (float*)d_out;             // [B, J, DOUT]

    char* ws = (char*)d_ws;
    ushort_t* Xt_hi  = (ushort_t*)(ws);                    //  4,718,592 B
    ushort_t* Xt_lo  = (ushort_t*)(ws + 4718592);          //  4,718,592 B
    ushort_t* Sbt_hi = (ushort_t*)(ws + 9437184);          //     81,920 B
    ushort_t* Sbt_lo = (ushort_t*)(ws + 9519104);          //     81,920 B
    float*    P      = (float*)   (ws + 9601024);          //  1,310,720 B
    float*    c      = (float*)   (ws + 10911744);         //     46,080 B
    float*    blog   = (float*)   (ws + 10957824);         //     46,080 B  (end ~11 MB)

    hipMemsetAsync(blog, 0, (size_t)I_ * J_ * sizeof(float), stream);
    prep_xt_kernel<<<2304, 256, 0, stream>>>(x, Xt_hi, Xt_lo);

    for (int it = 0; it < 3; ++it) {
        c_kernel<<<(I_ + 255) / 256, 256, 0, stream>>>(blog, c);
        gemm_s_kernel<<<320, 256, 0, stream>>>(x, W, c, (floatx4*)P);
        reduce_squash_kernel<<<160, 256, 0, stream>>>(P, s_out, Sbt_hi, Sbt_lo);
        if (it < 2)
            gemm_bupd_kernel<<<1440, 256, 0, stream>>>(Xt_hi, Xt_lo, Sbt_hi, Sbt_lo,
                                                       W, blog);
    }
}